// Round 6
// baseline (91.985 us; speedup 1.0000x reference)
//
#include <hip/hip_runtime.h>

#define NSEG 4096

__device__ __forceinline__ void acc4(float4& a, const float4 v) {
    a.x += v.x; a.y += v.y; a.z += v.z; a.w += v.w;
}

// ---------- K0: zero pooled + scatter bounds + transpose W ----------
// Grid covers max(524288 /*pooled float4s*/, nrows) threads.
__global__ __launch_bounds__(256) void setup_kernel(
    const int*   __restrict__ seg,    // [nrows] sorted
    const float* __restrict__ W,      // [32][512]
    int*         __restrict__ bounds, // [NSEG+1]
    float*       __restrict__ Wt,     // [512][32]
    float*       __restrict__ pooled, // [NSEG][512] (atomic target -> zero)
    int nrows)
{
    const int i = blockIdx.x * 256 + threadIdx.x;
    if (i < NSEG * 128) {   // 524288 float4s = 8 MB
        reinterpret_cast<float4*>(pooled)[i] = make_float4(0.f, 0.f, 0.f, 0.f);
    }
    if (i < 512 * 32) {
        const int d = i >> 5, j = i & 31;
        Wt[i] = W[j * 512 + d];
    }
    if (i >= nrows) return;
    const int cur  = seg[i];
    const int prev = (i == 0) ? -1 : seg[i - 1];
    for (int s = prev + 1; s <= cur; ++s) bounds[s] = i;
    if (i == nrows - 1) {
        for (int s = cur + 1; s <= NSEG; ++s) bounds[s] = nrows;
    }
}

// ---------- K1: uniform-chunk streaming pool with run-flush atomics ----------
// Wave g handles rows [16c, 16c+16) of emb e (c = g mod nchunk, e = g / nchunk).
// All 16 row-loads issued up front (16 float4 = 64 VGPRs in flight).
// Segment runs within the chunk flushed via atomicAdd (ids wave-uniform).
__global__ __launch_bounds__(256, 4) void pool_kernel(
    const float* __restrict__ emb_a,
    const float* __restrict__ emb_b,
    const int*   __restrict__ seg,     // [nrows]
    float*       __restrict__ pooled,  // [NSEG][512], pre-zeroed
    int nrows, int nchunk)
{
    const int t    = threadIdx.x;
    const int wave = t >> 6;
    const int lane = t & 63;
    const int g    = blockIdx.x * 4 + wave;
    if (g >= 2 * nchunk) return;

    const int e  = (g >= nchunk) ? 1 : 0;
    const int c  = g - e * nchunk;
    const int r0 = c << 4;

    const float*  base = e ? emb_b : emb_a;
    const float4* src  = reinterpret_cast<const float4*>(base) + (size_t)r0 * 64 + lane;
    const int     colbase = (e << 8) + (lane << 2);

    #define FLUSH(S, A) do {                                            \
        float* _p = pooled + (size_t)(S) * 512 + colbase;               \
        atomicAdd(_p + 0, (A).x); atomicAdd(_p + 1, (A).y);             \
        atomicAdd(_p + 2, (A).z); atomicAdd(_p + 3, (A).w);             \
    } while (0)

    if (r0 + 16 <= nrows) {
        // Fast path: all 16 loads in flight before any use.
        float4 v[16];
        #pragma unroll 16
        for (int k = 0; k < 16; ++k) v[k] = src[k * 64];
        int id[16];
        #pragma unroll 16
        for (int k = 0; k < 16; ++k) id[k] = seg[r0 + k];

        float4 acc = make_float4(0.f, 0.f, 0.f, 0.f);
        int cur = id[0];
        #pragma unroll 16
        for (int k = 0; k < 16; ++k) {
            if (id[k] != cur) {                 // wave-uniform branch
                FLUSH(cur, acc);
                acc = make_float4(0.f, 0.f, 0.f, 0.f);
                cur = id[k];
            }
            acc4(acc, v[k]);
        }
        FLUSH(cur, acc);
    } else if (r0 < nrows) {
        // Tail chunk (only when nrows % 16 != 0).
        float4 acc = make_float4(0.f, 0.f, 0.f, 0.f);
        int cur = seg[r0];
        for (int r = r0; r < nrows && r < r0 + 16; ++r) {
            const int idr = seg[r];
            if (idr != cur) {
                FLUSH(cur, acc);
                acc = make_float4(0.f, 0.f, 0.f, 0.f);
                cur = idr;
            }
            acc4(acc, src[(r - r0) * 64]);
        }
        FLUSH(cur, acc);
    }
    #undef FLUSH
}

// ---------- K2: out[seg][j] = dot(pooled[seg], Wt[:,j]) / cnt + b[j] ----------
// 512 blocks x 256 thr = 2048 waves (8/CU). Thread = (seg, j).
// Wt loads coalesced along j (lanes 0..31 read consecutive floats);
// pooled loads wave-uniform (scalar); unroll-8 for load pipelining.
__global__ __launch_bounds__(256) void proj_kernel(
    const float* __restrict__ pooled,  // [NSEG][512] (raw sums)
    const float* __restrict__ Wt,      // [512][32]
    const float* __restrict__ bias,    // [32]
    const int*   __restrict__ bounds,  // [NSEG+1]
    float*       __restrict__ out)     // [NSEG][32]
{
    const int t   = threadIdx.x;
    const int s   = blockIdx.x * 8 + (t >> 5);
    const int j   = t & 31;

    const float* P  = pooled + (size_t)s * 512;
    const float* wt = Wt + j;

    float sum = 0.f;
    #pragma unroll 8
    for (int d = 0; d < 512; ++d) {
        sum += P[d] * wt[(size_t)d * 32];
    }

    const int cnt = bounds[s + 1] - bounds[s];
    const float inv = 1.0f / (float)max(cnt, 1);
    out[(size_t)s * 32 + j] = sum * inv + bias[j];
}

// ---------- Fallback (ws too small): round-3 fused kernel, proven 38 us ----------
__global__ __launch_bounds__(128, 8) void fused_fallback_kernel(
    const float* __restrict__ emb_a,
    const float* __restrict__ emb_b,
    const int*   __restrict__ seg,
    const float* __restrict__ W,
    const float* __restrict__ bias,
    float*       __restrict__ out,
    int nrows)
{
    const int s = blockIdx.x;
    const int t = threadIdx.x;
    const int wave = t >> 6;
    const int lane = t & 63;
    __shared__ int   bnd[2];
    __shared__ float pooled[512];
    __shared__ float sh_out[32];
    if (t < 2) {
        int target = s + t;
        int lo = 0, hi = nrows;
        while (lo < hi) { int mid = (lo + hi) >> 1; if (seg[mid] < target) lo = mid + 1; else hi = mid; }
        bnd[t] = lo;
    }
    __syncthreads();
    const int start = bnd[0], end = bnd[1];
    const int cnt = end - start;
    const float*  base = (wave == 0) ? emb_a : emb_b;
    const float4* src  = reinterpret_cast<const float4*>(base) + lane;
    float4 a0{0,0,0,0}, a1{0,0,0,0}, a2{0,0,0,0}, a3{0,0,0,0};
    int r = start;
    for (; r + 4 <= end; r += 4) {
        float4 v0 = src[(size_t)(r+0)*64];
        float4 v1 = src[(size_t)(r+1)*64];
        float4 v2 = src[(size_t)(r+2)*64];
        float4 v3 = src[(size_t)(r+3)*64];
        acc4(a0, v0); acc4(a1, v1); acc4(a2, v2); acc4(a3, v3);
    }
    for (; r < end; ++r) acc4(a0, src[(size_t)r * 64]);
    const float inv = 1.0f / (float)max(cnt, 1);
    float4 acc;
    acc.x = (a0.x + a1.x + a2.x + a3.x) * inv;
    acc.y = (a0.y + a1.y + a2.y + a3.y) * inv;
    acc.z = (a0.z + a1.z + a2.z + a3.z) * inv;
    acc.w = (a0.w + a1.w + a2.w + a3.w) * inv;
    *reinterpret_cast<float4*>(pooled + (wave << 8) + (lane << 2)) = acc;
    __syncthreads();
    const float4* pool4 = reinterpret_cast<const float4*>(pooled);
    const float4  p0 = pool4[lane];
    const float4  p1 = pool4[64 + lane];
    #pragma unroll 4
    for (int jj = 0; jj < 16; ++jj) {
        const int j = (wave << 4) + jj;
        const float4* wrow = reinterpret_cast<const float4*>(W + j * 512);
        const float4  w0 = wrow[lane];
        const float4  w1 = wrow[64 + lane];
        float v = p0.x*w0.x + p0.y*w0.y + p0.z*w0.z + p0.w*w0.w
                + p1.x*w1.x + p1.y*w1.y + p1.z*w1.z + p1.w*w1.w;
        v += __shfl_xor(v, 1);
        v += __shfl_xor(v, 2);
        v += __shfl_xor(v, 4);
        v += __shfl_xor(v, 8);
        v += __shfl_xor(v, 16);
        v += __shfl_xor(v, 32);
        if (lane == 0) sh_out[j] = v + bias[j];
    }
    __syncthreads();
    if (t < 32) out[s * 32 + t] = sh_out[t];
}

extern "C" void kernel_launch(void* const* d_in, const int* in_sizes, int n_in,
                              void* d_out, int out_size, void* d_ws, size_t ws_size,
                              hipStream_t stream) {
    const float* emb_a = (const float*)d_in[0];
    const float* emb_b = (const float*)d_in[1];
    const int*   seg   = (const int*)d_in[2];
    const float* W     = (const float*)d_in[3];
    const float* bias  = (const float*)d_in[4];
    float*       out   = (float*)d_out;
    const int nrows = in_sizes[2];

    // ws layout: bounds @0 (4097 ints) | Wt @32768 (64 KB) | pooled @98304 (8 MB)
    const size_t OFF_WT     = 32768;
    const size_t OFF_POOLED = 98304;
    const size_t need       = OFF_POOLED + (size_t)NSEG * 512 * sizeof(float);

    if (ws_size >= need) {
        int*   bounds = (int*)d_ws;
        float* Wt     = (float*)((char*)d_ws + OFF_WT);
        float* pooled = (float*)((char*)d_ws + OFF_POOLED);

        const int zero_threads  = NSEG * 128;  // 524288 float4s
        const int setup_threads = (nrows > zero_threads) ? nrows : zero_threads;
        setup_kernel<<<(setup_threads + 255) / 256, 256, 0, stream>>>(
            seg, W, bounds, Wt, pooled, nrows);

        const int nchunk = (nrows + 15) >> 4;
        const int nwaves = 2 * nchunk;
        pool_kernel<<<(nwaves + 3) / 4, 256, 0, stream>>>(
            emb_a, emb_b, seg, pooled, nrows, nchunk);

        proj_kernel<<<NSEG / 8, 256, 0, stream>>>(pooled, Wt, bias, bounds, out);
    } else {
        fused_fallback_kernel<<<NSEG, 128, 0, stream>>>(emb_a, emb_b, seg, W, bias, out, nrows);
    }
}

// Round 7
// 76.687 us; speedup vs baseline: 1.1995x; 1.1995x over previous
//
#include <hip/hip_runtime.h>

#define NSEG    4096
#define NBLOCKS 2048   // static first-assignments; tickets cover [NBLOCKS, NSEG)

__device__ __forceinline__ void acc4(float4& a, const float4 v) {
    a.x += v.x; a.y += v.y; a.z += v.z; a.w += v.w;
}

// ---------- K0: scatter bounds + reset ticket ----------
__global__ __launch_bounds__(256) void setup_kernel(
    const int* __restrict__ seg,     // [nrows] sorted
    int*       __restrict__ ticket,  // [1]
    int*       __restrict__ bounds,  // [NSEG+1]
    int nrows)
{
    const int i = blockIdx.x * 256 + threadIdx.x;
    if (i == 0) *ticket = 0;
    if (i >= nrows) return;
    const int cur  = seg[i];
    const int prev = (i == 0) ? -1 : seg[i - 1];
    for (int s = prev + 1; s <= cur; ++s) bounds[s] = i;
    if (i == nrows - 1) {
        for (int s = cur + 1; s <= NSEG; ++s) bounds[s] = nrows;
    }
}

// ---------- K1: work-stealing fused pool + projection ----------
// 2048 blocks x 256 thr (4 waves) = 32 waves/CU, all resident.
// Block processes segment blockIdx.x, then steals 2048+atomicAdd(ticket,1)
// until exhausted. Inner body = round-4 structure (proven correct):
//   wave (e = w&1, half = w>>1): raw-sum its quarter; LDS combine;
//   phase-2: wave w owns j in [8w, 8w+8), W rows coalesced along lanes.
__global__ __launch_bounds__(256, 8) void fused_ws_kernel(
    const float* __restrict__ emb_a,
    const float* __restrict__ emb_b,
    const int*   __restrict__ bounds,  // [NSEG+1]
    const float* __restrict__ W,       // [32][512]
    const float* __restrict__ bias,    // [32]
    int*         __restrict__ ticket,  // [1], pre-zeroed
    float*       __restrict__ out)     // [NSEG][32]
{
    const int t    = threadIdx.x;
    const int wave = t >> 6;
    const int lane = t & 63;

    __shared__ float pooled[1024];   // [4 waves][256 cols] raw sums
    __shared__ float sh_out[32];
    __shared__ int   sh_s;

    const float*  base = (wave & 1) ? emb_b : emb_a;
    const float4* src  = reinterpret_cast<const float4*>(base) + lane; // row stride 64 float4

    int s = blockIdx.x;  // static first assignment (no atomic burst at launch)

    for (;;) {
        const int start = bounds[s];
        const int end   = bounds[s + 1];
        const int cnt   = end - start;
        const int mid   = start + (cnt >> 1);
        const int r0    = (wave >> 1) ? mid : start;
        const int r1    = (wave >> 1) ? end : mid;

        // ---- Phase 1: raw-sum pooling of this wave's quarter ----
        float4 a0{0,0,0,0}, a1{0,0,0,0}, a2{0,0,0,0}, a3{0,0,0,0};
        int r = r0;
        for (; r + 8 <= r1; r += 8) {
            float4 v0 = src[(size_t)(r+0)*64];
            float4 v1 = src[(size_t)(r+1)*64];
            float4 v2 = src[(size_t)(r+2)*64];
            float4 v3 = src[(size_t)(r+3)*64];
            float4 v4 = src[(size_t)(r+4)*64];
            float4 v5 = src[(size_t)(r+5)*64];
            float4 v6 = src[(size_t)(r+6)*64];
            float4 v7 = src[(size_t)(r+7)*64];
            acc4(a0, v0); acc4(a1, v1); acc4(a2, v2); acc4(a3, v3);
            acc4(a0, v4); acc4(a1, v5); acc4(a2, v6); acc4(a3, v7);
        }
        for (; r + 4 <= r1; r += 4) {
            float4 v0 = src[(size_t)(r+0)*64];
            float4 v1 = src[(size_t)(r+1)*64];
            float4 v2 = src[(size_t)(r+2)*64];
            float4 v3 = src[(size_t)(r+3)*64];
            acc4(a0, v0); acc4(a1, v1); acc4(a2, v2); acc4(a3, v3);
        }
        for (; r < r1; ++r) acc4(a0, src[(size_t)r * 64]);

        float4 acc;
        acc.x = a0.x + a1.x + a2.x + a3.x;
        acc.y = a0.y + a1.y + a2.y + a3.y;
        acc.z = a0.z + a1.z + a2.z + a3.z;
        acc.w = a0.w + a1.w + a2.w + a3.w;
        *reinterpret_cast<float4*>(pooled + (wave << 8) + (lane << 2)) = acc;
        __syncthreads();

        // ---- Combine halves + scale ----
        const float inv = 1.0f / (float)max(cnt, 1);
        const float4* pool4 = reinterpret_cast<const float4*>(pooled);
        const float4 qa0 = pool4[lane];         // emb_a, first half  (wave 0)
        const float4 qb0 = pool4[64 + lane];    // emb_b, first half  (wave 1)
        const float4 qa1 = pool4[128 + lane];   // emb_a, second half (wave 2)
        const float4 qb1 = pool4[192 + lane];   // emb_b, second half (wave 3)
        float4 p0, p1;
        p0.x = (qa0.x + qa1.x) * inv;  p0.y = (qa0.y + qa1.y) * inv;
        p0.z = (qa0.z + qa1.z) * inv;  p0.w = (qa0.w + qa1.w) * inv;
        p1.x = (qb0.x + qb1.x) * inv;  p1.y = (qb0.y + qb1.y) * inv;
        p1.z = (qb0.z + qb1.z) * inv;  p1.w = (qb0.w + qb1.w) * inv;

        // ---- Phase 2: projection, wave w owns j in [8w, 8w+8) ----
        #pragma unroll 4
        for (int jj = 0; jj < 8; ++jj) {
            const int j = (wave << 3) + jj;
            const float4* wrow = reinterpret_cast<const float4*>(W + j * 512);
            const float4  w0 = wrow[lane];        // d 0..255, 1KB wave-load
            const float4  w1 = wrow[64 + lane];   // d 256..511
            float v = p0.x*w0.x + p0.y*w0.y + p0.z*w0.z + p0.w*w0.w
                    + p1.x*w1.x + p1.y*w1.y + p1.z*w1.z + p1.w*w1.w;
            v += __shfl_xor(v, 1);
            v += __shfl_xor(v, 2);
            v += __shfl_xor(v, 4);
            v += __shfl_xor(v, 8);
            v += __shfl_xor(v, 16);
            v += __shfl_xor(v, 32);
            if (lane == 0) sh_out[j] = v + bias[j];
        }
        __syncthreads();

        if (t < 32) out[s * 32 + t] = sh_out[t];
        // sh_out is next written only after two more barriers -> safe.

        // ---- Steal next segment ----
        if (t == 0) sh_s = NBLOCKS + atomicAdd(ticket, 1);
        __syncthreads();
        s = sh_s;
        if (s >= NSEG) break;
    }
}

// ---------- Fallback (ws too small): round-3 fused kernel, proven 38 us ----------
__global__ __launch_bounds__(128, 8) void fused_fallback_kernel(
    const float* __restrict__ emb_a,
    const float* __restrict__ emb_b,
    const int*   __restrict__ seg,
    const float* __restrict__ W,
    const float* __restrict__ bias,
    float*       __restrict__ out,
    int nrows)
{
    const int s = blockIdx.x;
    const int t = threadIdx.x;
    const int wave = t >> 6;
    const int lane = t & 63;
    __shared__ int   bnd[2];
    __shared__ float pooled[512];
    __shared__ float sh_out[32];
    if (t < 2) {
        int target = s + t;
        int lo = 0, hi = nrows;
        while (lo < hi) { int mid = (lo + hi) >> 1; if (seg[mid] < target) lo = mid + 1; else hi = mid; }
        bnd[t] = lo;
    }
    __syncthreads();
    const int start = bnd[0], end = bnd[1];
    const int cnt = end - start;
    const float*  base = (wave == 0) ? emb_a : emb_b;
    const float4* src  = reinterpret_cast<const float4*>(base) + lane;
    float4 a0{0,0,0,0}, a1{0,0,0,0}, a2{0,0,0,0}, a3{0,0,0,0};
    int r = start;
    for (; r + 4 <= end; r += 4) {
        float4 v0 = src[(size_t)(r+0)*64];
        float4 v1 = src[(size_t)(r+1)*64];
        float4 v2 = src[(size_t)(r+2)*64];
        float4 v3 = src[(size_t)(r+3)*64];
        acc4(a0, v0); acc4(a1, v1); acc4(a2, v2); acc4(a3, v3);
    }
    for (; r < end; ++r) acc4(a0, src[(size_t)r * 64]);
    const float inv = 1.0f / (float)max(cnt, 1);
    float4 acc;
    acc.x = (a0.x + a1.x + a2.x + a3.x) * inv;
    acc.y = (a0.y + a1.y + a2.y + a3.y) * inv;
    acc.z = (a0.z + a1.z + a2.z + a3.z) * inv;
    acc.w = (a0.w + a1.w + a2.w + a3.w) * inv;
    *reinterpret_cast<float4*>(pooled + (wave << 8) + (lane << 2)) = acc;
    __syncthreads();
    const float4* pool4 = reinterpret_cast<const float4*>(pooled);
    const float4  p0 = pool4[lane];
    const float4  p1 = pool4[64 + lane];
    #pragma unroll 4
    for (int jj = 0; jj < 16; ++jj) {
        const int j = (wave << 4) + jj;
        const float4* wrow = reinterpret_cast<const float4*>(W + j * 512);
        const float4  w0 = wrow[lane];
        const float4  w1 = wrow[64 + lane];
        float v = p0.x*w0.x + p0.y*w0.y + p0.z*w0.z + p0.w*w0.w
                + p1.x*w1.x + p1.y*w1.y + p1.z*w1.z + p1.w*w1.w;
        v += __shfl_xor(v, 1);
        v += __shfl_xor(v, 2);
        v += __shfl_xor(v, 4);
        v += __shfl_xor(v, 8);
        v += __shfl_xor(v, 16);
        v += __shfl_xor(v, 32);
        if (lane == 0) sh_out[j] = v + bias[j];
    }
    __syncthreads();
    if (t < 32) out[s * 32 + t] = sh_out[t];
}

extern "C" void kernel_launch(void* const* d_in, const int* in_sizes, int n_in,
                              void* d_out, int out_size, void* d_ws, size_t ws_size,
                              hipStream_t stream) {
    const float* emb_a = (const float*)d_in[0];
    const float* emb_b = (const float*)d_in[1];
    const int*   seg   = (const int*)d_in[2];
    const float* W     = (const float*)d_in[3];
    const float* bias  = (const float*)d_in[4];
    float*       out   = (float*)d_out;
    const int nrows = in_sizes[2];

    // ws layout: ticket @0 (64B pad) | bounds @64 (4097 ints)
    const size_t need = 64 + (size_t)(NSEG + 1) * sizeof(int);
    if (ws_size >= need) {
        int* ticket = (int*)d_ws;
        int* bounds = (int*)((char*)d_ws + 64);
        setup_kernel<<<(nrows + 255) / 256, 256, 0, stream>>>(seg, ticket, bounds, nrows);
        fused_ws_kernel<<<NBLOCKS, 256, 0, stream>>>(emb_a, emb_b, bounds, W, bias, ticket, out);
    } else {
        fused_fallback_kernel<<<NSEG, 128, 0, stream>>>(emb_a, emb_b, seg, W, bias, out, nrows);
    }
}

// Round 8
// 39.600 us; speedup vs baseline: 2.3228x; 1.9365x over previous
//
#include <hip/hip_runtime.h>

#define NSEG 4096

__device__ __forceinline__ void acc4(float4& a, const float4 v) {
    a.x += v.x; a.y += v.y; a.z += v.z; a.w += v.w;
}

// Single fused kernel. 4096 blocks x 256 thr (4 waves).
// Block s: binary-search bounds (threads 0,1), then
//   wave (e = w&1, half = w>>1): raw-sum quarter of rows [start,end) of emb_e,
//   LDS combine + scale, phase-2: wave w owns j in [8w,8w+8),
//   W rows read coalesced along lanes, 6-step butterfly, coalesced store.
// launch_bounds(256,8): VGPR<=64 -> 8 blocks/CU residency for deep backfill.
__global__ __launch_bounds__(256, 8) void fused_kernel(
    const float* __restrict__ emb_a,
    const float* __restrict__ emb_b,
    const int*   __restrict__ seg,     // [nrows] sorted ascending
    const float* __restrict__ W,       // [32][512]
    const float* __restrict__ bias,    // [32]
    float*       __restrict__ out,     // [NSEG][32]
    int nrows)
{
    const int s    = blockIdx.x;
    const int t    = threadIdx.x;
    const int wave = t >> 6;
    const int lane = t & 63;

    __shared__ int   bnd[2];
    __shared__ float pooled[1024];   // [4 waves][256 cols] raw sums
    __shared__ float sh_out[32];

    // ---- segment bounds via lower_bound (16 iters, L1/L2-cached) ----
    if (t < 2) {
        int target = s + t;
        int lo = 0, hi = nrows;
        while (lo < hi) {
            int mid = (lo + hi) >> 1;
            if (seg[mid] < target) lo = mid + 1; else hi = mid;
        }
        bnd[t] = lo;
    }
    __syncthreads();
    const int start = bnd[0];
    const int end   = bnd[1];
    const int cnt   = end - start;
    const int mid   = start + (cnt >> 1);
    const int r0    = (wave >> 1) ? mid : start;
    const int r1    = (wave >> 1) ? end : mid;

    // ---- Phase 1: raw-sum pooling of this wave's quarter ----
    const float*  base = (wave & 1) ? emb_b : emb_a;
    const float4* src  = reinterpret_cast<const float4*>(base) + lane; // row stride 64 float4

    float4 a0{0,0,0,0}, a1{0,0,0,0}, a2{0,0,0,0}, a3{0,0,0,0};
    int r = r0;
    for (; r + 8 <= r1; r += 8) {
        float4 v0 = src[(size_t)(r+0)*64];
        float4 v1 = src[(size_t)(r+1)*64];
        float4 v2 = src[(size_t)(r+2)*64];
        float4 v3 = src[(size_t)(r+3)*64];
        float4 v4 = src[(size_t)(r+4)*64];
        float4 v5 = src[(size_t)(r+5)*64];
        float4 v6 = src[(size_t)(r+6)*64];
        float4 v7 = src[(size_t)(r+7)*64];
        acc4(a0, v0); acc4(a1, v1); acc4(a2, v2); acc4(a3, v3);
        acc4(a0, v4); acc4(a1, v5); acc4(a2, v6); acc4(a3, v7);
    }
    for (; r + 4 <= r1; r += 4) {
        float4 v0 = src[(size_t)(r+0)*64];
        float4 v1 = src[(size_t)(r+1)*64];
        float4 v2 = src[(size_t)(r+2)*64];
        float4 v3 = src[(size_t)(r+3)*64];
        acc4(a0, v0); acc4(a1, v1); acc4(a2, v2); acc4(a3, v3);
    }
    for (; r < r1; ++r) acc4(a0, src[(size_t)r * 64]);

    float4 acc;
    acc.x = a0.x + a1.x + a2.x + a3.x;
    acc.y = a0.y + a1.y + a2.y + a3.y;
    acc.z = a0.z + a1.z + a2.z + a3.z;
    acc.w = a0.w + a1.w + a2.w + a3.w;
    *reinterpret_cast<float4*>(pooled + (wave << 8) + (lane << 2)) = acc;
    __syncthreads();

    // ---- Combine halves + scale ----
    const float inv = 1.0f / (float)max(cnt, 1);
    const float4* pool4 = reinterpret_cast<const float4*>(pooled);
    const float4 qa0 = pool4[lane];         // emb_a, first half  (wave 0)
    const float4 qb0 = pool4[64 + lane];    // emb_b, first half  (wave 1)
    const float4 qa1 = pool4[128 + lane];   // emb_a, second half (wave 2)
    const float4 qb1 = pool4[192 + lane];   // emb_b, second half (wave 3)
    float4 p0, p1;
    p0.x = (qa0.x + qa1.x) * inv;  p0.y = (qa0.y + qa1.y) * inv;
    p0.z = (qa0.z + qa1.z) * inv;  p0.w = (qa0.w + qa1.w) * inv;
    p1.x = (qb0.x + qb1.x) * inv;  p1.y = (qb0.y + qb1.y) * inv;
    p1.z = (qb0.z + qb1.z) * inv;  p1.w = (qb0.w + qb1.w) * inv;

    // ---- Phase 2: projection, wave w owns j in [8w, 8w+8) ----
    #pragma unroll 4
    for (int jj = 0; jj < 8; ++jj) {
        const int j = (wave << 3) + jj;
        const float4* wrow = reinterpret_cast<const float4*>(W + j * 512);
        const float4  w0 = wrow[lane];        // d 0..255, 1KB wave-load (L1-hot)
        const float4  w1 = wrow[64 + lane];   // d 256..511
        float v = p0.x*w0.x + p0.y*w0.y + p0.z*w0.z + p0.w*w0.w
                + p1.x*w1.x + p1.y*w1.y + p1.z*w1.z + p1.w*w1.w;
        v += __shfl_xor(v, 1);
        v += __shfl_xor(v, 2);
        v += __shfl_xor(v, 4);
        v += __shfl_xor(v, 8);
        v += __shfl_xor(v, 16);
        v += __shfl_xor(v, 32);
        if (lane == 0) sh_out[j] = v + bias[j];
    }
    __syncthreads();

    // One coalesced 128B store per block.
    if (t < 32) out[s * 32 + t] = sh_out[t];
}

extern "C" void kernel_launch(void* const* d_in, const int* in_sizes, int n_in,
                              void* d_out, int out_size, void* d_ws, size_t ws_size,
                              hipStream_t stream) {
    const float* emb_a = (const float*)d_in[0];
    const float* emb_b = (const float*)d_in[1];
    const int*   seg   = (const int*)d_in[2];
    const float* W     = (const float*)d_in[3];
    const float* bias  = (const float*)d_in[4];
    float*       out   = (float*)d_out;
    const int nrows = in_sizes[2];

    fused_kernel<<<NSEG, 256, 0, stream>>>(emb_a, emb_b, seg, W, bias, out, nrows);
}